// Round 10
// baseline (253.490 us; speedup 1.0000x reference)
//
#include <hip/hip_runtime.h>
#include <hip/hip_bf16.h>
#include <stdint.h>

// ---------- types ----------
typedef __attribute__((ext_vector_type(8))) short bf16x8;
typedef __attribute__((ext_vector_type(4))) short short4v;
typedef __attribute__((ext_vector_type(4))) float f32x4;

#define DEV static __device__ __forceinline__

DEV float bf2f(short u) {
    union { float f; uint32_t i; } c; c.i = ((uint32_t)(uint16_t)u) << 16; return c.f;
}
DEV short f2bf(float f) {
    union { float f; uint32_t i; } c; c.f = f;
    uint32_t i = c.i;
    uint32_t r = i + 0x7FFFu + ((i >> 16) & 1u);   // RNE
    return (short)(r >> 16);
}

DEV void gload_lds16(const short* g, short* l) {
    __builtin_amdgcn_global_load_lds(
        (const __attribute__((address_space(1))) void*)g,
        (__attribute__((address_space(3))) void*)l,
        16, 0, 0);
}

// ---------- fp32 -> bf16 convert (8 elems/thread) ----------
__global__ __launch_bounds__(256)
void cvt_f32_bf16(const float* __restrict__ in, short* __restrict__ out) {
    long i = ((long)blockIdx.x * 256 + threadIdx.x) * 8;
    float4 a = *(const float4*)&in[i];
    float4 b = *(const float4*)&in[i + 4];
    bf16x8 o;
    o[0] = f2bf(a.x); o[1] = f2bf(a.y); o[2] = f2bf(a.z); o[3] = f2bf(a.w);
    o[4] = f2bf(b.x); o[5] = f2bf(b.y); o[6] = f2bf(b.z); o[7] = f2bf(b.w);
    *(bf16x8*)&out[i] = o;
}

// ---------- two fp32 -> bf16 converts in one dispatch (WQ, WK) ----------
__global__ __launch_bounds__(256)
void cvt2_f32_bf16(const float* __restrict__ inA, short* __restrict__ outA,
                   const float* __restrict__ inB, short* __restrict__ outB) {
    int blk = blockIdx.x;
    const float* in = (blk < 512) ? inA : inB;
    short* out      = (blk < 512) ? outA : outB;
    long i = ((long)(blk & 511) * 256 + threadIdx.x) * 8;
    float4 a = *(const float4*)&in[i];
    float4 b = *(const float4*)&in[i + 4];
    bf16x8 o;
    o[0] = f2bf(a.x); o[1] = f2bf(a.y); o[2] = f2bf(a.z); o[3] = f2bf(a.w);
    o[4] = f2bf(b.x); o[5] = f2bf(b.y); o[6] = f2bf(b.z); o[7] = f2bf(b.w);
    *(bf16x8*)&out[i] = o;
}

// ---------- W [H][D] fp32  ->  Wt [D][H] bf16 ----------
__global__ __launch_bounds__(256)
void transpose_w(const float* __restrict__ W, short* __restrict__ Wt) {
    const int HD = 1024;
    __shared__ float tile[32][33];
    int bx = blockIdx.x, by = blockIdx.y;
    int tx = threadIdx.x & 31, ty = threadIdx.x >> 5;  // 32 x 8
    #pragma unroll
    for (int r = ty; r < 32; r += 8)
        tile[r][tx] = W[(long)(by * 32 + r) * HD + bx * 32 + tx];
    __syncthreads();
    #pragma unroll
    for (int r = ty; r < 32; r += 8)
        Wt[(long)(bx * 32 + r) * HD + by * 32 + tx] = f2bf(tile[tx][r]);
}

// ---------- reduce 4 fp32 K-slices of Mt and cast to bf16 ----------
__global__ __launch_bounds__(256)
void reduce_mt(const float* __restrict__ Mpart, short* __restrict__ MTb) {
    const long SL = 1024L * 1024;
    long i = ((long)blockIdx.x * 256 + threadIdx.x) * 8;
    float s[8];
    #pragma unroll
    for (int j = 0; j < 8; ++j) s[j] = 0.f;
    #pragma unroll
    for (int sl = 0; sl < 4; ++sl) {
        float4 a = *(const float4*)&Mpart[sl * SL + i];
        float4 b = *(const float4*)&Mpart[sl * SL + i + 4];
        s[0] += a.x; s[1] += a.y; s[2] += a.z; s[3] += a.w;
        s[4] += b.x; s[5] += b.y; s[6] += b.z; s[7] += b.w;
    }
    bf16x8 o;
    #pragma unroll
    for (int j = 0; j < 8; ++j) o[j] = f2bf(s[j]);
    *(bf16x8*)&MTb[i] = o;
}

// ============================================================================
// 256x256 / BK=64 / 8-wave 8-phase GEMM (r5/r7 schedule — best measured; 4
// schedule variants r4/r5/r8/r9 all ~equal => structural ceiling for K=1024,
// matches guide's m248 reference family 666-848 TF).
// r10 change: EPILOGUES go through LDS (free after the K-loop) — scalar
// scattered stores (128 × 2B/thread, +30% write overfetch) replaced by
// XOR-swizzled LDS stage + linear read-back + 16B fully-coalesced stores.
// EPI: 0 = fused [G|V] projection, 1 = band scores (B = Xb), 2 = band PV,
//      3 = Mt split-K partial (fp32 out per K-slice)
// ============================================================================

DEV void stage_half(const short* __restrict__ src, int ld, short* dst, int tid) {
    int rr = tid >> 3;                                    // 0..63
    int cs = ((tid & 7) ^ (rr & 7)) << 3;                 // swizzled src col (shorts)
    short* d = dst + ((tid >> 6) << 9);                   // wave-uniform base
    gload_lds16(src + (long)rr * ld + cs, d);
    gload_lds16(src + (long)(rr + 64) * ld + cs, d + 4096);
}

DEV bf16x8 ld_frag(const short* half, int rowbase, int ks, int lane) {
    int row = rowbase + (lane & 15);
    int idx = (row << 6) + ks * 32 + ((lane >> 4) << 3);
    idx ^= (lane & 7) << 3;                               // read-side swizzle
    return *(const bf16x8*)&half[idx];
}

#define SCHED0 __builtin_amdgcn_sched_barrier(0)
#define SBAR do { SCHED0; __builtin_amdgcn_s_barrier(); SCHED0; } while (0)
#define LGK(n) do { asm volatile("s_waitcnt lgkmcnt(" #n ")" ::: "memory"); SCHED0; } while (0)
#define VM(n)  do { asm volatile("s_waitcnt vmcnt(" #n ")" ::: "memory"); SCHED0; } while (0)
#define PRIO1 __builtin_amdgcn_s_setprio(1)
#define PRIO0 __builtin_amdgcn_s_setprio(0)

#define READ_A(HP, QM)                                                          \
    do { _Pragma("unroll") for (int iq = 0; iq < 4; ++iq)                       \
         _Pragma("unroll") for (int ks = 0; ks < 2; ++ks)                       \
             ra[iq][ks] = ld_frag(HP, (QM)*64 + iq*16, ks, lane); } while (0)

#define READ_B(HP, QN)                                                          \
    do { _Pragma("unroll") for (int jn = 0; jn < 2; ++jn)                       \
         _Pragma("unroll") for (int ks = 0; ks < 2; ++ks)                       \
             rb[QN][jn][ks] = ld_frag(HP, wn1*64 + (QN)*32 + jn*16, ks, lane); } while (0)

#define MFMA_Q(QM, QN)                                                          \
    do { _Pragma("unroll") for (int iq = 0; iq < 4; ++iq)                       \
         _Pragma("unroll") for (int jn = 0; jn < 2; ++jn)                       \
         _Pragma("unroll") for (int ks = 0; ks < 2; ++ks)                       \
             acc[(QM)*4+iq][(QN)*2+jn] = __builtin_amdgcn_mfma_f32_16x16x32_bf16( \
                 ra[iq][ks], rb[QN][jn][ks], acc[(QM)*4+iq][(QN)*2+jn], 0,0,0); } while (0)

template<int EPI>
__global__ __launch_bounds__(512, 2)
void gemm256(const short* __restrict__ Abase, const short* __restrict__ Bbase,
             void* __restrict__ o0, void* __restrict__ o1, void* __restrict__ o2,
             const float* __restrict__ Crow, const float* __restrict__ Vsum)
{
    const int T = 2048, HD = 1024;
    __shared__ __align__(16) short lds[2][2][2][8192];   // [buf][A/B][half] 128 KiB

    const int tid  = threadIdx.x;
    const int lane = tid & 63;
    const int w    = tid >> 6;
    const int wm   = w >> 2;        // 0..1
    const int wn   = w & 3;         // 0..3
    const int wn1  = wn & 1;

    int m0, n0, klo, khi, ldA, ldB, bz;
    const short *A, *B;
    if (EPI == 0) {
        int p = (int)blockIdx.x + 8 * (int)blockIdx.y;    // 0..511
        int lid = (p & 7) * 64 + (p >> 3);                // XCD-chunked (512%8==0)
        m0 = (lid >> 3) * 256; n0 = (lid & 7) * 256;
        klo = 0; khi = 1024; ldA = HD; ldB = HD; bz = 0;
        A = Abase; B = Bbase;
    } else if (EPI == 1) {
        int p = (int)blockIdx.x + 3 * ((int)blockIdx.y + 8 * (int)blockIdx.z); // 0..191
        bz = p & 7; int rem = p >> 3;                     // batch -> XCD chunk
        int mb = rem / 3, kb = mb + rem % 3 - 1;
        if (kb < 0 || kb > 7) return;
        m0 = mb * 256; n0 = kb * 256;
        klo = 0; khi = 1024; ldA = HD; ldB = HD;
        A = Abase + (long)bz * T * HD; B = Bbase + (long)bz * T * HD;
    } else if (EPI == 2) {
        int p = (int)blockIdx.x + 4 * ((int)blockIdx.y + 8 * (int)blockIdx.z); // 0..255
        bz = p & 7; int rem = p >> 3;
        int mb = rem / 4;
        m0 = mb * 256; n0 = (rem % 4) * 256;
        klo = max(m0 - 256, 0); khi = min(m0 + 512, T);
        ldA = T; ldB = T;
        A = Abase + (long)bz * T * T; B = Bbase + (long)bz * HD * T;
    } else {
        // Mt split-K partial: z = K-slice
        m0 = blockIdx.y * 256; n0 = blockIdx.x * 256;
        klo = (int)blockIdx.z * 256; khi = klo + 256;
        ldA = HD; ldB = HD; bz = 0;
        A = Abase; B = Bbase;
    }

    const short* Asrc = A + (long)m0 * ldA + klo;
    const short* Bsrc = B + (long)n0 * ldB + klo;
    const short* hA0 = &lds[0][0][wm][0];
    const short* hA1 = &lds[1][0][wm][0];
    const short* hB0 = &lds[0][1][wn >> 1][0];
    const short* hB1 = &lds[1][1][wn >> 1][0];

    auto stA = [&](int bf, int hf, int t) {
        stage_half(Asrc + (long)hf * 128 * ldA + t * 64, ldA, (short*)&lds[bf][0][hf][0], tid); };
    auto stB = [&](int bf, int hf, int t) {
        stage_half(Bsrc + (long)hf * 128 * ldB + t * 64, ldB, (short*)&lds[bf][1][hf][0], tid); };

    f32x4 acc[8][4];
    #pragma unroll
    for (int i = 0; i < 8; ++i)
        #pragma unroll
        for (int j = 0; j < 4; ++j) { acc[i][j][0]=0.f; acc[i][j][1]=0.f; acc[i][j][2]=0.f; acc[i][j][3]=0.f; }
    bf16x8 ra[4][2];
    bf16x8 rb[2][2][2];

    const int NT = (khi - klo) >> 6;    // >= 2, even

    // prologue: tile0 {A,B} -> buf0, tile1 {B} -> buf1
    stB(0,0,0); stB(0,1,0); stA(0,0,0); stA(0,1,0); stB(1,0,1); stB(1,1,1);
    SCHED0; VM(4); SBAR;                 // buf0 landed for ALL waves
    READ_B(hB0, 0); SCHED0;              // early B-q0 for p0

    #pragma unroll 1
    for (int i = 0; i < NT/2 - 1; ++i) {
        int t1 = 2*i+1, t2 = 2*i+2, t3 = 2*i+3;
        // p0: tile 2i (buf0)
        SBAR; READ_A(hA0,0); SCHED0; READ_B(hB0,1); SCHED0; stA(1,0,t1);
        LGK(4); PRIO1; MFMA_Q(0,0); PRIO0; SCHED0;
        // p1
        SBAR; stA(1,1,t1); LGK(0); PRIO1; MFMA_Q(0,1); PRIO0; SCHED0;
        // p2  (buf0-B dead after p1 -> stage t2 B)
        SBAR; READ_A(hA0,1); SCHED0; stB(0,0,t2); LGK(0);
        PRIO1; MFMA_Q(1,0); PRIO0; SCHED0; VM(2); SCHED0;   // retire all but own stage
        // p3  (early B-q0 of buf1: safe, all waves did VM(2) before this barrier)
        SBAR; READ_B(hB1,0); SCHED0; stB(0,1,t2);
        PRIO1; MFMA_Q(1,1); PRIO0; SCHED0;
        // p4: tile 2i+1 (buf1)  (buf0-A dead after p2 -> stage t2 A)
        SBAR; READ_A(hA1,0); SCHED0; READ_B(hB1,1); SCHED0; stA(0,0,t2);
        LGK(4); PRIO1; MFMA_Q(0,0); PRIO0; SCHED0;
        // p5
        SBAR; stA(0,1,t2); LGK(0); PRIO1; MFMA_Q(0,1); PRIO0; SCHED0;
        // p6
        SBAR; READ_A(hA1,1); SCHED0; stB(1,0,t3); LGK(0);
        PRIO1; MFMA_Q(1,0); PRIO0; SCHED0; VM(2); SCHED0;
        // p7  (early B-q0 of buf0 for next iter)
        SBAR; READ_B(hB0,0); SCHED0; stB(1,1,t3);
        PRIO1; MFMA_Q(1,1); PRIO0; SCHED0;
    }
    {   // peeled final: tiles NT-2 (buf0), NT-1 (buf1); A of NT-1 staged here
        int t1 = NT - 1;
        SBAR; READ_A(hA0,0); SCHED0; READ_B(hB0,1); SCHED0; stA(1,0,t1);
        LGK(4); PRIO1; MFMA_Q(0,0); PRIO0; SCHED0;
        SBAR; stA(1,1,t1); LGK(0); PRIO1; MFMA_Q(0,1); PRIO0; SCHED0;
        SBAR; READ_A(hA0,1); SCHED0; LGK(0);
        PRIO1; MFMA_Q(1,0); PRIO0; SCHED0; VM(0); SCHED0;   // drain: buf1 fully landed
        SBAR; READ_B(hB1,0); SCHED0; PRIO1; MFMA_Q(1,1); PRIO0; SCHED0;
        SBAR; READ_A(hA1,0); SCHED0; READ_B(hB1,1); SCHED0;
        LGK(4); PRIO1; MFMA_Q(0,0); PRIO0; SCHED0;
        SBAR; LGK(0); PRIO1; MFMA_Q(0,1); PRIO0; SCHED0;
        SBAR; READ_A(hA1,1); SCHED0; LGK(0); PRIO1; MFMA_Q(1,0); PRIO0; SCHED0;
        SBAR; PRIO1; MFMA_Q(1,1); PRIO0; SCHED0;
    }
    // After the final SBAR every wave has drained its ds_reads (per-wave LGK(0))
    // and all DMA is retired (VM(0) in peel) -> LDS is free for the epilogue.

    // ---------------- epilogue (LDS-staged, coalesced stores) ----------------
    const int fr = lane & 15, fq = lane >> 4;
    char* ep = (char*)&lds[0][0][0][0];     // 128 KiB scratch

    if (EPI == 0) {
        const int wsel = n0 >> 10;          // 0=G, 1=V (block-uniform)
        if (wsel == 0) {
            // stage bf16 256x256 tile: byte = row*512 + (col*2 ^ ((row&7)<<4))
            #pragma unroll
            for (int mi = 0; mi < 8; ++mi)
                #pragma unroll
                for (int ni = 0; ni < 4; ++ni)
                    #pragma unroll
                    for (int r = 0; r < 4; ++r) {
                        int row = wm * 128 + mi * 16 + fq * 4 + r;
                        int col = wn * 64 + ni * 16 + fr;
                        *(short*)(ep + row * 512 + ((col * 2) ^ ((row & 7) << 4))) =
                            f2bf(acc[mi][ni][r]);
                    }
            SBAR;
            char* dst = (char*)o0;          // G row-major [16384][1024] bf16
            #pragma unroll
            for (int s = 0; s < 16; ++s) {
                int off = s * 8192 + tid * 16;
                int row = off >> 9, colb = off & 511;
                int4 v = *(int4*)(ep + row * 512 + (colb ^ ((row & 7) << 4)));
                *(int4*)(dst + (long)(m0 + row) * 2048 + n0 * 2 + colb) = v;
            }
        } else {
            // Vt[b][d][t]: stage TRANSPOSED (d-major rows of t)
            #pragma unroll
            for (int mi = 0; mi < 8; ++mi)
                #pragma unroll
                for (int ni = 0; ni < 4; ++ni)
                    #pragma unroll
                    for (int r = 0; r < 4; ++r) {
                        int tloc = wm * 128 + mi * 16 + fq * 4 + r;   // t within tile
                        int dloc = wn * 64 + ni * 16 + fr;            // d within tile
                        *(short*)(ep + dloc * 512 + ((tloc * 2) ^ ((dloc & 7) << 4))) =
                            f2bf(acc[mi][ni][r]);
                    }
            SBAR;
            int b = m0 >> 11, t0 = m0 & 2047, d0 = n0 & 1023;
            char* dst = (char*)o2;
            #pragma unroll
            for (int s = 0; s < 16; ++s) {
                int off = s * 8192 + tid * 16;
                int dloc = off >> 9, tb = off & 511;
                int4 v = *(int4*)(ep + dloc * 512 + (tb ^ ((dloc & 7) << 4)));
                *(int4*)(dst + ((long)(b * HD + d0 + dloc) * T + t0) * 2 + tb) = v;
            }
        }
    } else if (EPI == 1) {
        // band scores -> S (bf16), masked-to-0 outside band
        #pragma unroll
        for (int mi = 0; mi < 8; ++mi)
            #pragma unroll
            for (int ni = 0; ni < 4; ++ni)
                #pragma unroll
                for (int r = 0; r < 4; ++r) {
                    int row = wm * 128 + mi * 16 + fq * 4 + r;
                    int col = wn * 64 + ni * 16 + fr;
                    int i = m0 + row, j = n0 + col;
                    bool keep = (i - j <= 256) && (j - i <= 255);
                    *(short*)(ep + row * 512 + ((col * 2) ^ ((row & 7) << 4))) =
                        f2bf(keep ? acc[mi][ni][r] * (1.f / 32.f) : 0.f);
                }
        SBAR;
        char* dst = (char*)o0 + (long)bz * T * T * 2;
        #pragma unroll
        for (int s = 0; s < 16; ++s) {
            int off = s * 8192 + tid * 16;
            int row = off >> 9, colb = off & 511;
            int4 v = *(int4*)(ep + row * 512 + (colb ^ ((row & 7) << 4)));
            *(int4*)(dst + (long)(m0 + row) * 4096 + n0 * 2 + colb) = v;
        }
    } else if (EPI == 2) {
        // out fp32 + rank-1 correction: two 128-row passes through LDS
        char* dst = (char*)o0;
        #pragma unroll 1
        for (int pass = 0; pass < 2; ++pass) {
            if (wm == pass) {
                #pragma unroll
                for (int mi = 0; mi < 8; ++mi)
                    #pragma unroll
                    for (int r = 0; r < 4; ++r) {
                        int row = mi * 16 + fq * 4 + r;              // 0..127
                        float ci = Crow[bz * T + m0 + pass * 128 + row];
                        #pragma unroll
                        for (int ni = 0; ni < 4; ++ni) {
                            int col = wn * 64 + ni * 16 + fr;
                            float val = acc[mi][ni][r] + ci * Vsum[bz * HD + n0 + col];
                            *(float*)(ep + row * 1024 + ((col * 4) ^ ((row & 7) << 4))) = val;
                        }
                    }
            }
            SBAR;
            #pragma unroll
            for (int s = 0; s < 16; ++s) {
                int off = s * 8192 + tid * 16;
                int row = off >> 10, colb = off & 1023;
                int4 v = *(int4*)(ep + row * 1024 + (colb ^ ((row & 7) << 4)));
                *(int4*)(dst + ((long)bz * T + m0 + pass * 128 + row) * 4096 + n0 * 4 + colb) = v;
            }
            if (pass == 0) SBAR;
        }
    } else {
        // Mt split-K partial (tiny kernel) — plain stores
        float* dst = (float*)o0 + (long)blockIdx.z * HD * HD;
        #pragma unroll
        for (int mi = 0; mi < 8; ++mi)
            #pragma unroll
            for (int ni = 0; ni < 4; ++ni)
                #pragma unroll
                for (int r = 0; r < 4; ++r) {
                    int row = wm * 128 + m0 + mi * 16 + fq * 4 + r;
                    int col = wn * 64 + n0 + ni * 16 + fr;
                    dst[(long)row * HD + col] = acc[mi][ni][r];
                }
    }
}

// ---------- band softmax: in place P' = a - c; Crow[i] = c ----------
__global__ __launch_bounds__(256)
void softmax_band(short* __restrict__ S, float* __restrict__ Crow) {
    const int T = 2048;
    int wid = (int)blockIdx.x * 4 + (threadIdx.x >> 6);
    int lane = threadIdx.x & 63;
    int b = wid >> 11, t = wid & 2047;
    int mb = t >> 7;
    int tlo = max(mb - 2, 0) * 128;
    int thi = min(mb + 2, 15) * 128 + 128;
    int nvec = (thi - tlo) >> 3;                   // 48..80
    short* row = S + ((long)b * T + t) * T + tlo;

    bool h0 = lane < nvec;
    bool h1 = lane + 64 < nvec;
    bf16x8 v0, v1;
    float f0[8], f1[8];
    float m = 0.f;                                  // masked zeros always exist
    if (h0) {
        v0 = *(const bf16x8*)&row[lane * 8];
        #pragma unroll
        for (int j = 0; j < 8; ++j) { f0[j] = bf2f(v0[j]); m = fmaxf(m, f0[j]); }
    }
    if (h1) {
        v1 = *(const bf16x8*)&row[(lane + 64) * 8];
        #pragma unroll
        for (int j = 0; j < 8; ++j) { f1[j] = bf2f(v1[j]); m = fmaxf(m, f1[j]); }
    }
    #pragma unroll
    for (int o = 32; o; o >>= 1) m = fmaxf(m, __shfl_xor(m, o));

    float e0[8], e1[8];
    float sum = 0.f;
    if (h0) {
        #pragma unroll
        for (int j = 0; j < 8; ++j) { e0[j] = __expf(f0[j] - m); sum += e0[j]; }
    }
    if (h1) {
        #pragma unroll
        for (int j = 0; j < 8; ++j) { e1[j] = __expf(f1[j] - m); sum += e1[j]; }
    }
    #pragma unroll
    for (int o = 32; o; o >>= 1) sum += __shfl_xor(sum, o);
    float em = __expf(-m);
    sum += (float)(2048 - nvec * 8) * em;
    float inv = 1.f / sum;
    float c = em * inv;

    if (h0) {
        #pragma unroll
        for (int j = 0; j < 8; ++j) v0[j] = f2bf(e0[j] * inv - c);
        *(bf16x8*)&row[lane * 8] = v0;
    }
    if (h1) {
        #pragma unroll
        for (int j = 0; j < 8; ++j) v1[j] = f2bf(e1[j] * inv - c);
        *(bf16x8*)&row[(lane + 64) * 8] = v1;
    }
    if (lane == 0) Crow[wid] = c;
}

// ---------- Vsum[b][d] = sum_t Vt[b][d][t] ----------
__global__ __launch_bounds__(256)
void vsum_rows(const short* __restrict__ Vt, float* __restrict__ Vsum) {
    int rowid = (int)blockIdx.x * 4 + (threadIdx.x >> 6);
    int lane = threadIdx.x & 63;
    const short* r = Vt + (long)rowid * 2048;
    float s = 0.f;
    #pragma unroll
    for (int v = 0; v < 4; ++v) {
        bf16x8 x = *(const bf16x8*)&r[(lane + v * 64) * 8];
        #pragma unroll
        for (int j = 0; j < 8; ++j) s += bf2f(x[j]);
    }
    #pragma unroll
    for (int o = 32; o; o >>= 1) s += __shfl_xor(s, o);
    if (lane == 0) Vsum[rowid] = s;
}

// ---------- launch ----------
extern "C" void kernel_launch(void* const* d_in, const int* in_sizes, int n_in,
                              void* d_out, int out_size, void* d_ws, size_t ws_size,
                              hipStream_t stream) {
    const int B = 8, T = 2048, H = 1024, D = 1024;
    const long MT = (long)B * T;  // 16384

    const float* X  = (const float*)d_in[0];
    const float* WQ = (const float*)d_in[1];
    const float* WK = (const float*)d_in[2];
    const float* WV = (const float*)d_in[3];
    float* out = (float*)d_out;

    char* ws = (char*)d_ws;
    size_t off = 0;
    auto alloc = [&](size_t bytes) {
        char* p = ws + off;
        off += (bytes + 255) & ~(size_t)255;
        return p;
    };
    short* Xb    = (short*)alloc(MT * H * 2);          // 33.5 MB
    short* WQb   = (short*)alloc((long)H * D * 2);     //  2 MB (row-major bf16)
    short* WKb   = (short*)alloc((long)H * D * 2);     //  2 MB
    short* Bfuse = (short*)alloc(2L * D * H * 2);      //  4 MB: [Mt | WVt] contiguous
    short* MTb   = Bfuse;                              //  Mt = WK*WQ^T  [1024][1024]
    short* WVt   = Bfuse + (long)D * H;                //  WV^T [1024][1024]
    float* Mpart = (float*)alloc(4L * D * H * 4);      // 16 MB fp32 split-K partials
    short* Gb    = (short*)alloc(MT * D * 2);          // 33.5 MB  G = X*M
    short* Vt    = (short*)alloc((long)B * D * T * 2); // 33.5 MB  [b][d][t]
    short* S     = (short*)alloc((long)B * T * T * 2); // 67.1 MB  (band tiles only)
    float* Crow  = (float*)alloc(MT * 4);              // 64 KB
    float* Vsum  = (float*)alloc((long)B * D * 4);     // 32 KB
    if (off > ws_size) return;

    // 1) bf16 conversions
    cvt_f32_bf16<<<(int)(MT * H / 2048), 256, 0, stream>>>(X, Xb);
    cvt2_f32_bf16<<<1024, 256, 0, stream>>>(WQ, WQb, WK, WKb);
    transpose_w<<<dim3(32, 32), 256, 0, stream>>>(WV, WVt);

    // 2) Mt = WK * WQ^T, split-K over 4 slices (64 blocks) + reduce to bf16
    gemm256<3><<<dim3(4, 4, 4), 512, 0, stream>>>(WKb, WQb, Mpart, nullptr, nullptr, nullptr, nullptr);
    reduce_mt<<<512, 256, 0, stream>>>(Mpart, MTb);

    // 3) fused [G | V] projection: A = Xb, B = [Mt | WVt]  (N = 2048, 2 rounds)
    gemm256<0><<<dim3(8, 64, 1), 512, 0, stream>>>(Xb, Bfuse, Gb, nullptr, Vt, nullptr, nullptr);

    // 4) V column sums (rank-1 masked correction)
    vsum_rows<<<(int)(B * D / 4), 256, 0, stream>>>(Vt, Vsum);

    // 5) band scores: S = (G X^T)/32, B operand is Xb directly (K proj eliminated)
    gemm256<1><<<dim3(3, 8, B), 512, 0, stream>>>(Gb, Xb, S, nullptr, nullptr, nullptr, nullptr);

    // 6) band softmax -> P' = a - c in place, c per row
    softmax_band<<<(int)(MT / 4), 256, 0, stream>>>(S, Crow);

    // 7) band PV + rank-1 correction
    gemm256<2><<<dim3(4, 8, B), 512, 0, stream>>>(S, Vt, out, nullptr, nullptr, Crow, Vsum);
}

// Round 11
// 209.087 us; speedup vs baseline: 1.2124x; 1.2124x over previous
//
#include <hip/hip_runtime.h>
#include <hip/hip_bf16.h>
#include <stdint.h>

// ---------- types ----------
typedef __attribute__((ext_vector_type(8))) short bf16x8;
typedef __attribute__((ext_vector_type(4))) short short4v;
typedef __attribute__((ext_vector_type(4))) float f32x4;

#define DEV static __device__ __forceinline__

DEV float bf2f(short u) {
    union { float f; uint32_t i; } c; c.i = ((uint32_t)(uint16_t)u) << 16; return c.f;
}
DEV short f2bf(float f) {
    union { float f; uint32_t i; } c; c.f = f;
    uint32_t i = c.i;
    uint32_t r = i + 0x7FFFu + ((i >> 16) & 1u);   // RNE
    return (short)(r >> 16);
}

DEV void gload_lds16(const short* g, short* l) {
    __builtin_amdgcn_global_load_lds(
        (const __attribute__((address_space(1))) void*)g,
        (__attribute__((address_space(3))) void*)l,
        16, 0, 0);
}

// ---------- fused fp32 -> bf16 convert: X (8192 blk) | WQ (512) | WK (512) ----------
__global__ __launch_bounds__(256)
void cvt_all(const float* __restrict__ X, short* __restrict__ Xb,
             const float* __restrict__ WQ, short* __restrict__ WQb,
             const float* __restrict__ WK, short* __restrict__ WKb) {
    int blk = blockIdx.x;
    const float* in; short* out; int base;
    if (blk < 8192)      { in = X;  out = Xb;  base = blk; }
    else if (blk < 8704) { in = WQ; out = WQb; base = blk - 8192; }
    else                 { in = WK; out = WKb; base = blk - 8704; }
    long i = ((long)base * 256 + threadIdx.x) * 8;
    float4 a = *(const float4*)&in[i];
    float4 b = *(const float4*)&in[i + 4];
    bf16x8 o;
    o[0] = f2bf(a.x); o[1] = f2bf(a.y); o[2] = f2bf(a.z); o[3] = f2bf(a.w);
    o[4] = f2bf(b.x); o[5] = f2bf(b.y); o[6] = f2bf(b.z); o[7] = f2bf(b.w);
    *(bf16x8*)&out[i] = o;
}

// ---------- W [H][D] fp32  ->  Wt [D][H] bf16 ----------
__global__ __launch_bounds__(256)
void transpose_w(const float* __restrict__ W, short* __restrict__ Wt) {
    const int HD = 1024;
    __shared__ float tile[32][33];
    int bx = blockIdx.x, by = blockIdx.y;
    int tx = threadIdx.x & 31, ty = threadIdx.x >> 5;  // 32 x 8
    #pragma unroll
    for (int r = ty; r < 32; r += 8)
        tile[r][tx] = W[(long)(by * 32 + r) * HD + bx * 32 + tx];
    __syncthreads();
    #pragma unroll
    for (int r = ty; r < 32; r += 8)
        Wt[(long)(bx * 32 + r) * HD + by * 32 + tx] = f2bf(tile[tx][r]);
}

// ---------- reduce 4 fp32 K-slices of Mt and cast to bf16 ----------
__global__ __launch_bounds__(256)
void reduce_mt(const float* __restrict__ Mpart, short* __restrict__ MTb) {
    const long SL = 1024L * 1024;
    long i = ((long)blockIdx.x * 256 + threadIdx.x) * 8;
    float s[8];
    #pragma unroll
    for (int j = 0; j < 8; ++j) s[j] = 0.f;
    #pragma unroll
    for (int sl = 0; sl < 4; ++sl) {
        float4 a = *(const float4*)&Mpart[sl * SL + i];
        float4 b = *(const float4*)&Mpart[sl * SL + i + 4];
        s[0] += a.x; s[1] += a.y; s[2] += a.z; s[3] += a.w;
        s[4] += b.x; s[5] += b.y; s[6] += b.z; s[7] += b.w;
    }
    bf16x8 o;
    #pragma unroll
    for (int j = 0; j < 8; ++j) o[j] = f2bf(s[j]);
    *(bf16x8*)&MTb[i] = o;
}

// ============================================================================
// 256x256 / BK=64 / 8-wave 8-phase GEMM — r7 schedule (best measured 209.7us).
// Closed experiments: r6 dual-bank pipelining -> VGPR spill (FETCH x3);
// r4/r5/r8/r9 wait-schedule variants -> all ~equal (structural ceiling at
// K=1024, consistent with guide m248 666-848 TF family); r10 LDS-staged
// epilogue -> bank conflicts + write overfetch. Do not revisit.
// EPI: 0 = fused [G|V] projection, 1 = band scores (B = Xb), 2 = band PV,
//      3 = Mt split-K partial (fp32 out per K-slice)
// ============================================================================

DEV void stage_half(const short* __restrict__ src, int ld, short* dst, int tid) {
    int rr = tid >> 3;                                    // 0..63
    int cs = ((tid & 7) ^ (rr & 7)) << 3;                 // swizzled src col (shorts)
    short* d = dst + ((tid >> 6) << 9);                   // wave-uniform base
    gload_lds16(src + (long)rr * ld + cs, d);
    gload_lds16(src + (long)(rr + 64) * ld + cs, d + 4096);
}

DEV bf16x8 ld_frag(const short* half, int rowbase, int ks, int lane) {
    int row = rowbase + (lane & 15);
    int idx = (row << 6) + ks * 32 + ((lane >> 4) << 3);
    idx ^= (lane & 7) << 3;                               // read-side swizzle
    return *(const bf16x8*)&half[idx];
}

#define SCHED0 __builtin_amdgcn_sched_barrier(0)
#define SBAR do { SCHED0; __builtin_amdgcn_s_barrier(); SCHED0; } while (0)
#define LGK(n) do { asm volatile("s_waitcnt lgkmcnt(" #n ")" ::: "memory"); SCHED0; } while (0)
#define VM(n)  do { asm volatile("s_waitcnt vmcnt(" #n ")" ::: "memory"); SCHED0; } while (0)
#define PRIO1 __builtin_amdgcn_s_setprio(1)
#define PRIO0 __builtin_amdgcn_s_setprio(0)

#define READ_A(HP, QM)                                                          \
    do { _Pragma("unroll") for (int iq = 0; iq < 4; ++iq)                       \
         _Pragma("unroll") for (int ks = 0; ks < 2; ++ks)                       \
             ra[iq][ks] = ld_frag(HP, (QM)*64 + iq*16, ks, lane); } while (0)

#define READ_B(HP, QN)                                                          \
    do { _Pragma("unroll") for (int jn = 0; jn < 2; ++jn)                       \
         _Pragma("unroll") for (int ks = 0; ks < 2; ++ks)                       \
             rb[QN][jn][ks] = ld_frag(HP, wn1*64 + (QN)*32 + jn*16, ks, lane); } while (0)

#define MFMA_Q(QM, QN)                                                          \
    do { _Pragma("unroll") for (int iq = 0; iq < 4; ++iq)                       \
         _Pragma("unroll") for (int jn = 0; jn < 2; ++jn)                       \
         _Pragma("unroll") for (int ks = 0; ks < 2; ++ks)                       \
             acc[(QM)*4+iq][(QN)*2+jn] = __builtin_amdgcn_mfma_f32_16x16x32_bf16( \
                 ra[iq][ks], rb[QN][jn][ks], acc[(QM)*4+iq][(QN)*2+jn], 0,0,0); } while (0)

template<int EPI>
__global__ __launch_bounds__(512, 2)
void gemm256(const short* __restrict__ Abase, const short* __restrict__ Bbase,
             void* __restrict__ o0, void* __restrict__ o1, void* __restrict__ o2,
             const float* __restrict__ Crow, const float* __restrict__ Vsum)
{
    const int T = 2048, HD = 1024;
    __shared__ __align__(16) short lds[2][2][2][8192];   // [buf][A/B][half] 128 KiB

    const int tid  = threadIdx.x;
    const int lane = tid & 63;
    const int w    = tid >> 6;
    const int wm   = w >> 2;        // 0..1
    const int wn   = w & 3;         // 0..3
    const int wn1  = wn & 1;

    int m0, n0, klo, khi, ldA, ldB, bz;
    const short *A, *B;
    if (EPI == 0) {
        int p = (int)blockIdx.x + 8 * (int)blockIdx.y;    // 0..511
        int lid = (p & 7) * 64 + (p >> 3);                // XCD-chunked (512%8==0)
        m0 = (lid >> 3) * 256; n0 = (lid & 7) * 256;
        klo = 0; khi = 1024; ldA = HD; ldB = HD; bz = 0;
        A = Abase; B = Bbase;
    } else if (EPI == 1) {
        int p = (int)blockIdx.x + 3 * ((int)blockIdx.y + 8 * (int)blockIdx.z); // 0..191
        bz = p & 7; int rem = p >> 3;                     // batch -> XCD chunk
        int mb = rem / 3, kb = mb + rem % 3 - 1;
        if (kb < 0 || kb > 7) return;
        m0 = mb * 256; n0 = kb * 256;
        klo = 0; khi = 1024; ldA = HD; ldB = HD;
        A = Abase + (long)bz * T * HD; B = Bbase + (long)bz * T * HD;
    } else if (EPI == 2) {
        int p = (int)blockIdx.x + 4 * ((int)blockIdx.y + 8 * (int)blockIdx.z); // 0..255
        bz = p & 7; int rem = p >> 3;
        int mb = rem / 4;
        m0 = mb * 256; n0 = (rem % 4) * 256;
        klo = max(m0 - 256, 0); khi = min(m0 + 512, T);
        ldA = T; ldB = T;
        A = Abase + (long)bz * T * T; B = Bbase + (long)bz * HD * T;
    } else {
        // Mt split-K partial: z = K-slice
        m0 = blockIdx.y * 256; n0 = blockIdx.x * 256;
        klo = (int)blockIdx.z * 256; khi = klo + 256;
        ldA = HD; ldB = HD; bz = 0;
        A = Abase; B = Bbase;
    }

    const short* Asrc = A + (long)m0 * ldA + klo;
    const short* Bsrc = B + (long)n0 * ldB + klo;
    const short* hA0 = &lds[0][0][wm][0];
    const short* hA1 = &lds[1][0][wm][0];
    const short* hB0 = &lds[0][1][wn >> 1][0];
    const short* hB1 = &lds[1][1][wn >> 1][0];

    auto stA = [&](int bf, int hf, int t) {
        stage_half(Asrc + (long)hf * 128 * ldA + t * 64, ldA, (short*)&lds[bf][0][hf][0], tid); };
    auto stB = [&](int bf, int hf, int t) {
        stage_half(Bsrc + (long)hf * 128 * ldB + t * 64, ldB, (short*)&lds[bf][1][hf][0], tid); };

    f32x4 acc[8][4];
    #pragma unroll
    for (int i = 0; i < 8; ++i)
        #pragma unroll
        for (int j = 0; j < 4; ++j) { acc[i][j][0]=0.f; acc[i][j][1]=0.f; acc[i][j][2]=0.f; acc[i][j][3]=0.f; }
    bf16x8 ra[4][2];
    bf16x8 rb[2][2][2];

    const int NT = (khi - klo) >> 6;    // >= 2, even

    // prologue: tile0 {A,B} -> buf0, tile1 {B} -> buf1
    stB(0,0,0); stB(0,1,0); stA(0,0,0); stA(0,1,0); stB(1,0,1); stB(1,1,1);
    SCHED0; VM(4); SBAR;                 // buf0 landed for ALL waves
    READ_B(hB0, 0); SCHED0;              // early B-q0 for p0

    #pragma unroll 1
    for (int i = 0; i < NT/2 - 1; ++i) {
        int t1 = 2*i+1, t2 = 2*i+2, t3 = 2*i+3;
        // p0: tile 2i (buf0)
        SBAR; READ_A(hA0,0); SCHED0; READ_B(hB0,1); SCHED0; stA(1,0,t1);
        LGK(4); PRIO1; MFMA_Q(0,0); PRIO0; SCHED0;
        // p1
        SBAR; stA(1,1,t1); LGK(0); PRIO1; MFMA_Q(0,1); PRIO0; SCHED0;
        // p2  (buf0-B dead after p1 -> stage t2 B)
        SBAR; READ_A(hA0,1); SCHED0; stB(0,0,t2); LGK(0);
        PRIO1; MFMA_Q(1,0); PRIO0; SCHED0; VM(2); SCHED0;   // retire all but own stage
        // p3  (early B-q0 of buf1: safe, all waves did VM(2) before this barrier)
        SBAR; READ_B(hB1,0); SCHED0; stB(0,1,t2);
        PRIO1; MFMA_Q(1,1); PRIO0; SCHED0;
        // p4: tile 2i+1 (buf1)  (buf0-A dead after p2 -> stage t2 A)
        SBAR; READ_A(hA1,0); SCHED0; READ_B(hB1,1); SCHED0; stA(0,0,t2);
        LGK(4); PRIO1; MFMA_Q(0,0); PRIO0; SCHED0;
        // p5
        SBAR; stA(0,1,t2); LGK(0); PRIO1; MFMA_Q(0,1); PRIO0; SCHED0;
        // p6
        SBAR; READ_A(hA1,1); SCHED0; stB(1,0,t3); LGK(0);
        PRIO1; MFMA_Q(1,0); PRIO0; SCHED0; VM(2); SCHED0;
        // p7  (early B-q0 of buf0 for next iter)
        SBAR; READ_B(hB0,0); SCHED0; stB(1,1,t3);
        PRIO1; MFMA_Q(1,1); PRIO0; SCHED0;
    }
    {   // peeled final: tiles NT-2 (buf0), NT-1 (buf1); A of NT-1 staged here
        int t1 = NT - 1;
        SBAR; READ_A(hA0,0); SCHED0; READ_B(hB0,1); SCHED0; stA(1,0,t1);
        LGK(4); PRIO1; MFMA_Q(0,0); PRIO0; SCHED0;
        SBAR; stA(1,1,t1); LGK(0); PRIO1; MFMA_Q(0,1); PRIO0; SCHED0;
        SBAR; READ_A(hA0,1); SCHED0; LGK(0);
        PRIO1; MFMA_Q(1,0); PRIO0; SCHED0; VM(0); SCHED0;   // drain: buf1 fully landed
        SBAR; READ_B(hB1,0); SCHED0; PRIO1; MFMA_Q(1,1); PRIO0; SCHED0;
        SBAR; READ_A(hA1,0); SCHED0; READ_B(hB1,1); SCHED0;
        LGK(4); PRIO1; MFMA_Q(0,0); PRIO0; SCHED0;
        SBAR; LGK(0); PRIO1; MFMA_Q(0,1); PRIO0; SCHED0;
        SBAR; READ_A(hA1,1); SCHED0; LGK(0); PRIO1; MFMA_Q(1,0); PRIO0; SCHED0;
        SBAR; PRIO1; MFMA_Q(1,1); PRIO0; SCHED0;
    }

    // ---------------- epilogue ----------------
    const int fr = lane & 15, fq = lane >> 4;
    const int rbase = m0 + wm * 128, cbase = n0 + wn * 64;

    if (EPI == 0) {
        const int wsel = n0 >> 10;          // 0=G, 1=V (block-uniform)
        if (wsel == 0) {
            short* dst = (short*)o0;        // G row-major [16384][1024]
            #pragma unroll
            for (int mi = 0; mi < 8; ++mi)
                #pragma unroll
                for (int ni = 0; ni < 4; ++ni)
                    #pragma unroll
                    for (int r = 0; r < 4; ++r) {
                        int row = rbase + mi * 16 + fq * 4 + r;
                        int col = cbase + ni * 16 + fr;
                        dst[(long)row * HD + col] = f2bf(acc[mi][ni][r]);
                    }
        } else {
            short* Vt = (short*)o2;         // [b][d][t]
            #pragma unroll
            for (int mi = 0; mi < 8; ++mi)
                #pragma unroll
                for (int ni = 0; ni < 4; ++ni) {
                    int col  = (cbase + ni * 16 + fr) & 1023;
                    int row0 = rbase + mi * 16 + fq * 4;
                    int b = row0 >> 11, t = row0 & 2047;
                    short4v v;
                    #pragma unroll
                    for (int r = 0; r < 4; ++r) v[r] = f2bf(acc[mi][ni][r]);
                    *(short4v*)&Vt[((long)b * HD + col) * T + t] = v;
                }
        }
    } else if (EPI == 1) {
        short* S = (short*)o0 + (long)bz * T * T;
        #pragma unroll
        for (int mi = 0; mi < 8; ++mi)
            #pragma unroll
            for (int ni = 0; ni < 4; ++ni)
                #pragma unroll
                for (int r = 0; r < 4; ++r) {
                    int i = rbase + mi * 16 + fq * 4 + r;
                    int j = cbase + ni * 16 + fr;
                    bool keep = (i - j <= 256) && (j - i <= 255);
                    S[(long)i * T + j] = f2bf(keep ? acc[mi][ni][r] * (1.f/32.f) : 0.f);
                }
    } else if (EPI == 2) {
        float* out = (float*)o0;
        #pragma unroll
        for (int mi = 0; mi < 8; ++mi)
            #pragma unroll
            for (int r = 0; r < 4; ++r) {
                int i = rbase + mi * 16 + fq * 4 + r;
                float ci = Crow[bz * T + i];
                #pragma unroll
                for (int ni = 0; ni < 4; ++ni) {
                    int col = cbase + ni * 16 + fr;
                    out[((long)bz * T + i) * HD + col] = acc[mi][ni][r] + ci * Vsum[bz * HD + col];
                }
            }
    } else {
        float* dst = (float*)o0 + (long)blockIdx.z * HD * HD;   // fp32 partial slice
        #pragma unroll
        for (int mi = 0; mi < 8; ++mi)
            #pragma unroll
            for (int ni = 0; ni < 4; ++ni)
                #pragma unroll
                for (int r = 0; r < 4; ++r) {
                    int row = rbase + mi * 16 + fq * 4 + r;
                    int col = cbase + ni * 16 + fr;
                    dst[(long)row * HD + col] = acc[mi][ni][r];
                }
    }
}

// ---------- band softmax: in place P' = a - c; Crow[i] = c ----------
__global__ __launch_bounds__(256)
void softmax_band(short* __restrict__ S, float* __restrict__ Crow) {
    const int T = 2048;
    int wid = (int)blockIdx.x * 4 + (threadIdx.x >> 6);
    int lane = threadIdx.x & 63;
    int b = wid >> 11, t = wid & 2047;
    int mb = t >> 7;
    int tlo = max(mb - 2, 0) * 128;
    int thi = min(mb + 2, 15) * 128 + 128;
    int nvec = (thi - tlo) >> 3;                   // 48..80
    short* row = S + ((long)b * T + t) * T + tlo;

    bool h0 = lane < nvec;
    bool h1 = lane + 64 < nvec;
    bf16x8 v0, v1;
    float f0[8], f1[8];
    float m = 0.f;                                  // masked zeros always exist
    if (h0) {
        v0 = *(const bf16x8*)&row[lane * 8];
        #pragma unroll
        for (int j = 0; j < 8; ++j) { f0[j] = bf2f(v0[j]); m = fmaxf(m, f0[j]); }
    }
    if (h1) {
        v1 = *(const bf16x8*)&row[(lane + 64) * 8];
        #pragma unroll
        for (int j = 0; j < 8; ++j) { f1[j] = bf2f(v1[j]); m = fmaxf(m, f1[j]); }
    }
    #pragma unroll
    for (int o = 32; o; o >>= 1) m = fmaxf(m, __shfl_xor(m, o));

    float e0[8], e1[8];
    float sum = 0.f;
    if (h0) {
        #pragma unroll
        for (int j = 0; j < 8; ++j) { e0[j] = __expf(f0[j] - m); sum += e0[j]; }
    }
    if (h1) {
        #pragma unroll
        for (int j = 0; j < 8; ++j) { e1[j] = __expf(f1[j] - m); sum += e1[j]; }
    }
    #pragma unroll
    for (int o = 32; o; o >>= 1) sum += __shfl_xor(sum, o);
    float em = __expf(-m);
    sum += (float)(2048 - nvec * 8) * em;
    float inv = 1.f / sum;
    float c = em * inv;

    if (h0) {
        #pragma unroll
        for (int j = 0; j < 8; ++j) v0[j] = f2bf(e0[j] * inv - c);
        *(bf16x8*)&row[lane * 8] = v0;
    }
    if (h1) {
        #pragma unroll
        for (int j = 0; j < 8; ++j) v1[j] = f2bf(e1[j] * inv - c);
        *(bf16x8*)&row[(lane + 64) * 8] = v1;
    }
    if (lane == 0) Crow[wid] = c;
}

// ---------- Vsum[b][d] = sum_t Vt[b][d][t] ----------
__global__ __launch_bounds__(256)
void vsum_rows(const short* __restrict__ Vt, float* __restrict__ Vsum) {
    int rowid = (int)blockIdx.x * 4 + (threadIdx.x >> 6);
    int lane = threadIdx.x & 63;
    const short* r = Vt + (long)rowid * 2048;
    float s = 0.f;
    #pragma unroll
    for (int v = 0; v < 4; ++v) {
        bf16x8 x = *(const bf16x8*)&r[(lane + v * 64) * 8];
        #pragma unroll
        for (int j = 0; j < 8; ++j) s += bf2f(x[j]);
    }
    #pragma unroll
    for (int o = 32; o; o >>= 1) s += __shfl_xor(s, o);
    if (lane == 0) Vsum[rowid] = s;
}

// ---------- launch ----------
extern "C" void kernel_launch(void* const* d_in, const int* in_sizes, int n_in,
                              void* d_out, int out_size, void* d_ws, size_t ws_size,
                              hipStream_t stream) {
    const int B = 8, T = 2048, H = 1024, D = 1024;
    const long MT = (long)B * T;  // 16384

    const float* X  = (const float*)d_in[0];
    const float* WQ = (const float*)d_in[1];
    const float* WK = (const float*)d_in[2];
    const float* WV = (const float*)d_in[3];
    float* out = (float*)d_out;

    char* ws = (char*)d_ws;
    size_t off = 0;
    auto alloc = [&](size_t bytes) {
        char* p = ws + off;
        off += (bytes + 255) & ~(size_t)255;
        return p;
    };
    short* Xb    = (short*)alloc(MT * H * 2);          // 33.5 MB
    short* WQb   = (short*)alloc((long)H * D * 2);     //  2 MB (row-major bf16)
    short* WKb   = (short*)alloc((long)H * D * 2);     //  2 MB
    short* Bfuse = (short*)alloc(2L * D * H * 2);      //  4 MB: [Mt | WVt] contiguous
    short* MTb   = Bfuse;                              //  Mt = WK*WQ^T  [1024][1024]
    short* WVt   = Bfuse + (long)D * H;                //  WV^T [1024][1024]
    float* Mpart = (float*)alloc(4L * D * H * 4);      // 16 MB fp32 split-K partials
    short* Gb    = (short*)alloc(MT * D * 2);          // 33.5 MB  G = X*M
    short* Vt    = (short*)alloc((long)B * D * T * 2); // 33.5 MB  [b][d][t]
    short* S     = (short*)alloc((long)B * T * T * 2); // 67.1 MB  (band tiles only)
    float* Crow  = (float*)alloc(MT * 4);              // 64 KB
    float* Vsum  = (float*)alloc((long)B * D * 4);     // 32 KB
    if (off > ws_size) return;

    // 1) bf16 conversions (X, WQ, WK in ONE dispatch) + WV transpose
    cvt_all<<<8192 + 1024, 256, 0, stream>>>(X, Xb, WQ, WQb, WK, WKb);
    transpose_w<<<dim3(32, 32), 256, 0, stream>>>(WV, WVt);

    // 2) Mt = WK * WQ^T, split-K over 4 slices (64 blocks) + reduce to bf16
    gemm256<3><<<dim3(4, 4, 4), 512, 0, stream>>>(WKb, WQb, Mpart, nullptr, nullptr, nullptr, nullptr);
    reduce_mt<<<512, 256, 0, stream>>>(Mpart, MTb);

    // 3) fused [G | V] projection: A = Xb, B = [Mt | WVt]  (N = 2048, 2 rounds)
    gemm256<0><<<dim3(8, 64, 1), 512, 0, stream>>>(Xb, Bfuse, Gb, nullptr, Vt, nullptr, nullptr);

    // 4) V column sums (rank-1 masked correction)
    vsum_rows<<<(int)(B * D / 4), 256, 0, stream>>>(Vt, Vsum);

    // 5) band scores: S = (G X^T)/32, B operand is Xb directly (K proj eliminated)
    gemm256<1><<<dim3(3, 8, B), 512, 0, stream>>>(Gb, Xb, S, nullptr, nullptr, nullptr, nullptr);

    // 6) band softmax -> P' = a - c in place, c per row
    softmax_band<<<(int)(MT / 4), 256, 0, stream>>>(S, Crow);

    // 7) band PV + rank-1 correction
    gemm256<2><<<dim3(4, 8, B), 512, 0, stream>>>(S, Vt, out, nullptr, nullptr, Crow, Vsum);
}